// Round 9
// baseline (245.766 us; speedup 1.0000x reference)
//
#include <hip/hip_runtime.h>
#include <cstdint>
#include <cstddef>

// ---------------------------------------------------------------------------
// Hgru2 (GLA-style gated linear attention), B=4, N=2048, d=1024, h=8, hd=128
//   cast_all: x -> bf16; W -> bf16 (Wo gets norm_w folded into its columns)
//   gemm_qkv: Q=silu(xWq^T), K=1-sigmoid(xWk^T) (bf16), V (bf16)
//   hgru_scan (C=32, fused): recompute U_{c-1} from chunk c-1 in LDS (1-term
//       state, per-chunk decay <= e^-10), O = tril(Qh Kt^T) V + Qh U; also
//       accumulates Ssum[row] = sum_v O^2 via quad-reduce + atomicAdd.
//   gemm_out: out[m][n] = rsqrt(Ssum[m]/1024+eps) * (O @ (Wo . w)^T)[m][n]
// R9: gemm_out re-tiled 128x64 (1024 blocks, 24KB LDS dbuf -> 4-5 blocks/CU,
//     was 512 blocks @ 2/CU with zero multi-round overlap); sumsq fused into
//     scan epilogue (atomicAdd, memsetAsync init); casts merged to 1 launch.
// ---------------------------------------------------------------------------

typedef unsigned short u16;
using f32x4  = __attribute__((ext_vector_type(4))) float;
using bf16x8 = __attribute__((ext_vector_type(8))) short;

__device__ __forceinline__ float bf2f(u16 u) {
  union { unsigned int i; float f; } v; v.i = ((unsigned int)u) << 16; return v.f;
}
__device__ __forceinline__ u16 f2bf(float f) {
  union { float f; unsigned int i; } v; v.f = f;
  unsigned int r = v.i + 0x7fffu + ((v.i >> 16) & 1u);
  return (u16)(r >> 16);
}
__device__ __forceinline__ void async_load16(const void* g, void* l) {
  __builtin_amdgcn_global_load_lds(
      (const __attribute__((address_space(1))) unsigned int*)(uintptr_t)g,
      (__attribute__((address_space(3))) unsigned int*)(uintptr_t)l, 16, 0, 0);
}

// ---------------------------------------------------------------------------
// 128x128-tile bf16 GEMM core (R7): BK=32, double-buffered in 32KB,
// 1 barrier/kt, loads age a full compute phase before the drain.
// ---------------------------------------------------------------------------
__device__ __forceinline__ void gemm128_core(const u16* __restrict__ Ag, const u16* __restrict__ Bg,
                                             u16* smem, f32x4 (&acc)[4][4]) {
  const int tid = threadIdx.x;
  const int lane = tid & 63, wave = tid >> 6;
  const int wm = (wave & 1) * 64, wn = (wave >> 1) * 64;
  const int r = lane & 15, quad = lane >> 4;
  const int xk = r & 3;
  const u16* baseA = smem + (wm + r) * 32 + ((quad ^ xk) & 3) * 8;
  const u16* baseB = smem + 4096 + (wn + r) * 32 + ((quad ^ xk) & 3) * 8;
  const int soff = (tid >> 2) * 1024 + (((tid & 3) ^ ((tid >> 2) & 3)) * 8);
  u16* dA = smem + wave * 512;           // + it*2048 + buf*8192
  u16* dB = smem + 4096 + wave * 512;
#pragma unroll
  for (int it = 0; it < 2; ++it) {
    async_load16(Ag + it * 65536 + soff, dA + it * 2048);
    async_load16(Bg + it * 65536 + soff, dB + it * 2048);
  }
#pragma unroll 2
  for (int kt = 0; kt < 32; ++kt) {
    const int cb = (kt & 1) * 8192;
    __syncthreads();
    if (kt < 31) {
      const int nb = ((kt + 1) & 1) * 8192;
      const u16* As = Ag + (kt + 1) * 32 + soff;
      const u16* Bs = Bg + (kt + 1) * 32 + soff;
#pragma unroll
      for (int it = 0; it < 2; ++it) {
        async_load16(As + it * 65536, dA + nb + it * 2048);
        async_load16(Bs + it * 65536, dB + nb + it * 2048);
      }
    }
    bf16x8 af[4], bv[4];
#pragma unroll
    for (int i = 0; i < 4; ++i) af[i] = *(const bf16x8*)(baseA + cb + i * 512);
#pragma unroll
    for (int j = 0; j < 4; ++j) bv[j] = *(const bf16x8*)(baseB + cb + j * 512);
#pragma unroll
    for (int i = 0; i < 4; ++i)
#pragma unroll
      for (int j = 0; j < 4; ++j)
        acc[i][j] = __builtin_amdgcn_mfma_f32_16x16x32_bf16(af[i], bv[j], acc[i][j], 0, 0, 0);
  }
}

// ---------------------------------------------------------------------------
// 128x64-tile variant for gemm_out: A tile 128 rows, B tile 64 rows, BK=32,
// double-buffered in 24KB (A0 B0 A1 B1 = 8K 4K 8K 4K), 1 barrier/kt.
// ---------------------------------------------------------------------------
__device__ __forceinline__ void gemm64_core(const u16* __restrict__ Ag, const u16* __restrict__ Bg,
                                            u16* smem, f32x4 (&acc)[4][2]) {
  const int tid = threadIdx.x;
  const int lane = tid & 63, wave = tid >> 6;
  const int wm = (wave & 1) * 64, wn = (wave >> 1) * 32;
  const int r = lane & 15, quad = lane >> 4;
  const int xk = r & 3;
  const u16* baseA = smem + (wm + r) * 32 + ((quad ^ xk) & 3) * 8;
  const u16* baseB = smem + 4096 + (wn + r) * 32 + ((quad ^ xk) & 3) * 8;
  const int soff = (tid >> 2) * 1024 + (((tid & 3) ^ ((tid >> 2) & 3)) * 8);
  u16* dA = smem + wave * 512;           // 2 its of 64 rows; + buf*6144
  u16* dB = smem + 4096 + wave * 512;    // 1 it of 64 rows
#pragma unroll
  for (int it = 0; it < 2; ++it) async_load16(Ag + it * 65536 + soff, dA + it * 2048);
  async_load16(Bg + soff, dB);
#pragma unroll 2
  for (int kt = 0; kt < 32; ++kt) {
    const int cb = (kt & 1) * 6144;
    __syncthreads();
    if (kt < 31) {
      const int nb = ((kt + 1) & 1) * 6144;
      const u16* As = Ag + (kt + 1) * 32 + soff;
      const u16* Bs = Bg + (kt + 1) * 32 + soff;
#pragma unroll
      for (int it = 0; it < 2; ++it) async_load16(As + it * 65536, dA + nb + it * 2048);
      async_load16(Bs, dB + nb);
    }
    bf16x8 af[4], bv[2];
#pragma unroll
    for (int i = 0; i < 4; ++i) af[i] = *(const bf16x8*)(baseA + cb + i * 512);
#pragma unroll
    for (int j = 0; j < 2; ++j) bv[j] = *(const bf16x8*)(baseB + cb + j * 512);
#pragma unroll
    for (int i = 0; i < 4; ++i)
#pragma unroll
      for (int j = 0; j < 2; ++j)
        acc[i][j] = __builtin_amdgcn_mfma_f32_16x16x32_bf16(af[i], bv[j], acc[i][j], 0, 0, 0);
  }
}

// ---------------------------------------------------------------------------
// merged casts: blocks 0-8191 -> x (2M float4); blocks 8192-12287 -> weights
// (Wo gets norm_w folded).
__global__ __launch_bounds__(256) void cast_all(
    const float* __restrict__ x, const float* __restrict__ w0, const float* __restrict__ w1,
    const float* __restrict__ w2, const float* __restrict__ w3, const float* __restrict__ nw,
    u16* __restrict__ xd, u16* __restrict__ d0, u16* __restrict__ d1,
    u16* __restrict__ d2, u16* __restrict__ d3) {
  const int blk = blockIdx.x;
  const float* src;
  u16* dst;
  int i;
  bool fold = false;
  if (blk < 8192) {
    src = x; dst = xd; i = blk * 256 + threadIdx.x;
  } else {
    int wb = blk - 8192, which = wb >> 10;
    i = (wb & 1023) * 256 + threadIdx.x;
    src = which == 0 ? w0 : (which == 1 ? w1 : (which == 2 ? w2 : w3));
    dst = which == 0 ? d0 : (which == 1 ? d1 : (which == 2 ? d2 : d3));
    fold = (which == 3);
  }
  float4 v = ((const float4*)src)[i];
  if (fold) {
    float4 wv = ((const float4*)nw)[i & 255];
    v.x *= wv.x; v.y *= wv.y; v.z *= wv.z; v.w *= wv.w;
  }
  unsigned int lo = (unsigned)f2bf(v.x) | ((unsigned)f2bf(v.y) << 16);
  unsigned int hi = (unsigned)f2bf(v.z) | ((unsigned)f2bf(v.w) << 16);
  ((uint2*)dst)[i] = make_uint2(lo, hi);
}

// grid (64, 24): y/8 selects {Q,K,V}, y&7 = 128-col block
__global__ __launch_bounds__(256) void hgru_gemm_qkv(
    const u16* __restrict__ Xb, const u16* __restrict__ Wqb, const u16* __restrict__ Wkb,
    const u16* __restrict__ Wvb, u16* __restrict__ Qb, u16* __restrict__ Kb,
    u16* __restrict__ Vb) {
  __shared__ alignas(16) u16 smem[16384];
  const int which = blockIdx.y >> 3, bn = blockIdx.y & 7;
  const u16* W = which == 0 ? Wqb : (which == 1 ? Wkb : Wvb);
  const u16* Ag = Xb + (size_t)blockIdx.x * 128 * 1024;
  const u16* Bg = W + (size_t)bn * 128 * 1024;
  f32x4 acc[4][4] = {};
  gemm128_core(Ag, Bg, smem, acc);
  const int tid = threadIdx.x, lane = tid & 63, wave = tid >> 6;
  const int wm = (wave & 1) * 64, wn = (wave >> 1) * 64;
  const int r = lane & 15, quad = lane >> 4;
#pragma unroll
  for (int i = 0; i < 4; ++i)
#pragma unroll
    for (int j = 0; j < 4; ++j)
#pragma unroll
      for (int reg = 0; reg < 4; ++reg) {
        int m = blockIdx.x * 128 + wm + i * 16 + quad * 4 + reg;
        int n = bn * 128 + wn + j * 16 + r;
        size_t off = (size_t)m * 1024 + n;
        float z = acc[i][j][reg];
        if (which == 0) {
          Qb[off] = f2bf(z / (1.f + __expf(-z)));      // silu
        } else if (which == 1) {
          float ek = __expf(-z);
          Kb[off] = f2bf(ek / (1.f + ek));              // k = 1 - sigmoid(z)
        } else {
          Vb[off] = f2bf(z);
        }
      }
}

// ---------------------------------------------------------------------------
// Fused scan (R8 layout, 42496 B, 3 blocks/CU) + fused sumsq (R9).
// grid 4096: vh = blk&1, c = (blk>>1)&63 (C=32), bh = blk>>7.
// ---------------------------------------------------------------------------
__global__ __launch_bounds__(256) void hgru_scan(
    const u16* __restrict__ Qg, const u16* __restrict__ Kg, const u16* __restrict__ Vg,
    u16* __restrict__ O, float* __restrict__ Ssum) {
  __shared__ alignas(16) char smem[42496];
  float* sb  = (float*)(smem);             // [32][129] cumsum    [0,16512)
  u16* sU    = (u16*)(smem);               // [64][136] U^T       [0,17408)  after transform-c
  u16* sKt   = (u16*)(smem + 17408);       // [128][40] phase1
  u16* sVt1  = (u16*)(smem + 27648);       // [64][40]  phase1
  u16* sQ    = (u16*)(smem + 17408);       // [32][136] phase2
  u16* sK    = (u16*)(smem + 26112);       // [32][136] phase2
  u16* sVt2  = (u16*)(smem + 34816);       // [64][40]
  u16* sAm   = (u16*)(smem + 39936);       // [32][40]

  const int tid = threadIdx.x, blk = blockIdx.x;
  const int vh = blk & 1, c = (blk >> 1) & 63, bh = blk >> 7, h = bh & 7, bb_ = bh >> 3;
  const size_t rb = (size_t)(bb_ * 2048 + c * 32) * 1024 + h * 128;
  const bool haveP = (c > 0);
  const size_t rb1 = haveP ? rb - 32 * 1024 : rb;

  const int lane = tid & 63, wave = tid >> 6;
  const int r = lane & 15, quad = lane >> 4;
  const int ts = tid & 31;
  const int g8 = tid >> 5;

  uint4 Q2[2], K2[2], K1[2], V2, V1;
#pragma unroll
  for (int it = 0; it < 2; ++it) {
    Q2[it] = *(const uint4*)(Qg + rb  + (size_t)ts * 1024 + (it * 8 + g8) * 8);
    K2[it] = *(const uint4*)(Kg + rb  + (size_t)ts * 1024 + (it * 8 + g8) * 8);
    K1[it] = *(const uint4*)(Kg + rb1 + (size_t)ts * 1024 + (it * 8 + g8) * 8);
  }
  V2 = *(const uint4*)(Vg + rb  + (size_t)ts * 1024 + vh * 64 + g8 * 8);
  V1 = *(const uint4*)(Vg + rb1 + (size_t)ts * 1024 + vh * 64 + g8 * 8);

  f32x4 accU[2][4] = {};
  const int vm = (wave & 1) * 32, in = (wave >> 1) * 64;

  if (haveP) {
    { const int col = tid & 127, half = tid >> 7;
      float run = 0.f;
      const size_t gb = rb1 + (size_t)(half * 16) * 1024 + col;
#pragma unroll
      for (int t = 0; t < 16; ++t) {
        float kv = bf2f(Kg[gb + (size_t)t * 1024]);
        run -= __logf(1.f + __expf(-(1.f - kv)));
        sb[(half * 16 + t) * 129 + col] = run;
      } }
    __syncthreads();
    { if (tid >> 7) { const int col = tid & 127; float fix = sb[15 * 129 + col];
#pragma unroll
        for (int t = 16; t < 32; ++t) sb[t * 129 + col] += fix; } }
    __syncthreads();
#pragma unroll
    for (int it = 0; it < 2; ++it) {
      const int i8 = it * 8 + g8;
      const u16* kp = (const u16*)&K1[it];
#pragma unroll
      for (int e = 0; e < 8; ++e) {
        int i = i8 * 8 + e;
        float bs = sb[ts * 129 + i];
        float bC = sb[31 * 129 + i];
        sKt[i * 40 + ts] = f2bf(bf2f(kp[e]) * __expf(bC - bs));
      }
    }
    { const u16* vp = (const u16*)&V1;
#pragma unroll
      for (int e = 0; e < 8; ++e) sVt1[(g8 * 8 + e) * 40 + ts] = vp[e]; }
    __syncthreads();
#pragma unroll
    for (int mi = 0; mi < 2; ++mi) {
      bf16x8 af = *(const bf16x8*)(sVt1 + (vm + mi * 16 + r) * 40 + quad * 8);
#pragma unroll
      for (int nj = 0; nj < 4; ++nj) {
        bf16x8 bv = *(const bf16x8*)(sKt + (in + nj * 16 + r) * 40 + quad * 8);
        accU[mi][nj] = __builtin_amdgcn_mfma_f32_16x16x32_bf16(af, bv, accU[mi][nj], 0, 0, 0);
      }
    }
  }
  { const int col = tid & 127, half = tid >> 7;
    float run = 0.f;
    const size_t gb = rb + (size_t)(half * 16) * 1024 + col;
#pragma unroll
    for (int t = 0; t < 16; ++t) {
      float kv = bf2f(Kg[gb + (size_t)t * 1024]);
      run -= __logf(1.f + __expf(-(1.f - kv)));
      sb[(half * 16 + t) * 129 + col] = run;
    } }
  __syncthreads();
  { if (tid >> 7) { const int col = tid & 127; float fix = sb[15 * 129 + col];
#pragma unroll
      for (int t = 16; t < 32; ++t) sb[t * 129 + col] += fix; } }
  __syncthreads();
#pragma unroll
  for (int it = 0; it < 2; ++it) {
    const int i8 = it * 8 + g8;
    const u16* qp = (const u16*)&Q2[it];
    const u16* kp = (const u16*)&K2[it];
    u16 qo[8], ko[8];
#pragma unroll
    for (int e = 0; e < 8; ++e) {
      int i = i8 * 8 + e;
      float bt = sb[ts * 129 + i];
      qo[e] = f2bf(bf2f(qp[e]) * __expf(bt));
      ko[e] = f2bf(bf2f(kp[e]) * __expf(-bt));
    }
    *(uint4*)(sQ + ts * 136 + i8 * 8) = *(const uint4*)qo;
    *(uint4*)(sK + ts * 136 + i8 * 8) = *(const uint4*)ko;
  }
  { const u16* vp = (const u16*)&V2;
#pragma unroll
    for (int e = 0; e < 8; ++e) sVt2[(g8 * 8 + e) * 40 + ts] = vp[e]; }
  __syncthreads();
  { const int mi = wave & 1, nj = wave >> 1;
    f32x4 a1 = {0.f, 0.f, 0.f, 0.f};
#pragma unroll
    for (int ks = 0; ks < 4; ++ks) {
      bf16x8 af = *(const bf16x8*)(sQ + (mi * 16 + r) * 136 + ks * 32 + quad * 8);
      bf16x8 bk = *(const bf16x8*)(sK + (nj * 16 + r) * 136 + ks * 32 + quad * 8);
      a1 = __builtin_amdgcn_mfma_f32_16x16x32_bf16(af, bk, a1, 0, 0, 0);
    }
#pragma unroll
    for (int reg = 0; reg < 4; ++reg) {
      int t = mi * 16 + quad * 4 + reg, s = nj * 16 + r;
      sAm[t * 40 + s] = (s <= t) ? f2bf(a1[reg]) : (u16)0;
    } }
  if (haveP) {
#pragma unroll
    for (int mi = 0; mi < 2; ++mi)
#pragma unroll
      for (int nj = 0; nj < 4; ++nj)
#pragma unroll
        for (int reg = 0; reg < 4; ++reg) {
          int vl = vm + mi * 16 + quad * 4 + reg;
          int i  = in + nj * 16 + r;
          sU[vl * 136 + i] = f2bf(accU[mi][nj][reg]);
        }
  }
  __syncthreads();
  // GEMM2 + fused sumsq
  { const int mi = wave & 1, no = (wave >> 1) * 32;
    bf16x8 af0 = *(const bf16x8*)(sAm + (mi * 16 + r) * 40 + quad * 8);
    bf16x8 afq[4];
    if (haveP) {
#pragma unroll
      for (int ks = 0; ks < 4; ++ks)
        afq[ks] = *(const bf16x8*)(sQ + (mi * 16 + r) * 136 + ks * 32 + quad * 8);
    }
    f32x4 ssq = {0.f, 0.f, 0.f, 0.f};
#pragma unroll
    for (int j = 0; j < 2; ++j) {
      f32x4 acc2 = {0.f, 0.f, 0.f, 0.f};
      bf16x8 bv0 = *(const bf16x8*)(sVt2 + (no + j * 16 + r) * 40 + quad * 8);
      acc2 = __builtin_amdgcn_mfma_f32_16x16x32_bf16(af0, bv0, acc2, 0, 0, 0);
      if (haveP) {
#pragma unroll
        for (int ks = 0; ks < 4; ++ks) {
          bf16x8 bs = *(const bf16x8*)(sU + (no + j * 16 + r) * 136 + ks * 32 + quad * 8);
          acc2 = __builtin_amdgcn_mfma_f32_16x16x32_bf16(afq[ks], bs, acc2, 0, 0, 0);
        }
      }
      ssq += acc2 * acc2;
#pragma unroll
      for (int reg = 0; reg < 4; ++reg) {
        int t = mi * 16 + quad * 4 + reg;
        int vg = vh * 64 + no + j * 16 + r;
        O[rb + (size_t)t * 1024 + vg] = f2bf(acc2[reg]);
      }
    }
    const int rowg = bb_ * 2048 + c * 32 + mi * 16 + quad * 4;
#pragma unroll
    for (int reg = 0; reg < 4; ++reg) {
      float v = ssq[reg];
      v += __shfl_xor(v, 1); v += __shfl_xor(v, 2);
      v += __shfl_xor(v, 4); v += __shfl_xor(v, 8);
      if (r == 0) atomicAdd(&Ssum[rowg + reg], v);
    } }
}

// out[m][n] = rsqrt(Ssum[m]/1024+eps) * (O @ Wo'^T)[m][n]; grid (64,16)
__global__ __launch_bounds__(256) void hgru_gemm_out(const u16* __restrict__ Ab,
                                                     const u16* __restrict__ Wob,
                                                     const float* __restrict__ Ssum,
                                                     float* __restrict__ out) {
  __shared__ alignas(16) u16 smem[12288];
  const u16* Ag = Ab + (size_t)blockIdx.x * 128 * 1024;
  const u16* Bg = Wob + (size_t)blockIdx.y * 64 * 1024;
  f32x4 acc[4][2] = {};
  gemm64_core(Ag, Bg, smem, acc);
  const int tid = threadIdx.x, lane = tid & 63, wave = tid >> 6;
  const int wm = (wave & 1) * 64, wn = (wave >> 1) * 32;
  const int r = lane & 15, quad = lane >> 4;
#pragma unroll
  for (int i = 0; i < 4; ++i)
#pragma unroll
    for (int reg = 0; reg < 4; ++reg) {
      int m = blockIdx.x * 128 + wm + i * 16 + quad * 4 + reg;
      float sm = rsqrtf(Ssum[m] * (1.f / 1024.f) + 1e-6f);
#pragma unroll
      for (int j = 0; j < 2; ++j) {
        int n = blockIdx.y * 64 + wn + j * 16 + r;
        out[(size_t)m * 1024 + n] = acc[i][j][reg] * sm;
      }
    }
}

// ---------------------------------------------------------------------------
extern "C" void kernel_launch(void* const* d_in, const int* in_sizes, int n_in,
                              void* d_out, int out_size, void* d_ws, size_t ws_size,
                              hipStream_t stream) {
  const float* x  = (const float*)d_in[0];
  const float* Wq = (const float*)d_in[1];
  const float* Wk = (const float*)d_in[2];
  const float* Wv = (const float*)d_in[3];
  const float* Wo = (const float*)d_in[4];
  const float* nw = (const float*)d_in[5];
  float* out = (float*)d_out;
  char* ws = (char*)d_ws;

  u16* Xb   = (u16*)(ws + 0);            // 16 MB
  u16* Wqb  = (u16*)(ws + 16777216);
  u16* Wkb  = (u16*)(ws + 18874368);
  u16* Wvb  = (u16*)(ws + 20971520);
  u16* Wob  = (u16*)(ws + 23068672);
  u16* Qb   = (u16*)(ws + 25165824);     // 16 MB
  u16* Kb   = (u16*)(ws + 41943040);     // 16 MB
  u16* Vb   = (u16*)(ws + 58720256);     // 16 MB
  u16* Obf  = (u16*)(ws + 75497472);     // 16 MB scan output
  float* Sv = (float*)(ws + 92274688);   // 32 KB row sum-of-squares

  cast_all<<<12288, 256, 0, stream>>>(x, Wq, Wk, Wv, Wo, nw, Xb, Wqb, Wkb, Wvb, Wob);
  hipMemsetAsync(Sv, 0, 8192 * sizeof(float), stream);

  dim3 gq(64, 24);
  hgru_gemm_qkv<<<gq, 256, 0, stream>>>(Xb, Wqb, Wkb, Wvb, Qb, Kb, Vb);
  hgru_scan<<<4096, 256, 0, stream>>>(Qb, Kb, Vb, Obf, Sv);
  dim3 go(64, 16);
  hgru_gemm_out<<<go, 256, 0, stream>>>(Obf, Wob, Sv, out);
}

// Round 10
// 238.305 us; speedup vs baseline: 1.0313x; 1.0313x over previous
//
#include <hip/hip_runtime.h>
#include <cstdint>
#include <cstddef>

// ---------------------------------------------------------------------------
// Hgru2 (GLA-style gated linear attention), B=4, N=2048, d=1024, h=8, hd=128
//   cast_all: x -> bf16; W -> bf16 (Wo gets norm_w folded into its columns)
//   gemm_qkv: Q=silu(xWq^T), K=1-sigmoid(xWk^T) (bf16), V (bf16)
//   hgru_scan (C=32, fused): recompute U_{c-1} from chunk c-1 in LDS (1-term
//       state, per-chunk decay <= e^-10), O = tril(Qh Kt^T) V + Qh U; also
//       accumulates Ssum[row] = sum_v O^2 via quad-reduce + atomicAdd.
//   gemm_out: out[m][n] = rsqrt(Ssum[m]/1024+eps) * (O @ (Wo . w)^T)[m][n]
// R10: gemm_out reverted to 128x128/32KB core (R9's 128x64 halved MFMA-per-
//      barrier and lost ~8us); scan cumsum logsigmoid via softplus series
//      (-ln2+f/2-f^2/8+f^4/192-f^6/2880, err<2.5e-5 on (0,1)) -> no
//      quarter-rate exp/log in the cumsum phases.
// ---------------------------------------------------------------------------

typedef unsigned short u16;
using f32x4  = __attribute__((ext_vector_type(4))) float;
using bf16x8 = __attribute__((ext_vector_type(8))) short;

__device__ __forceinline__ float bf2f(u16 u) {
  union { unsigned int i; float f; } v; v.i = ((unsigned int)u) << 16; return v.f;
}
__device__ __forceinline__ u16 f2bf(float f) {
  union { float f; unsigned int i; } v; v.f = f;
  unsigned int r = v.i + 0x7fffu + ((v.i >> 16) & 1u);
  return (u16)(r >> 16);
}
__device__ __forceinline__ void async_load16(const void* g, void* l) {
  __builtin_amdgcn_global_load_lds(
      (const __attribute__((address_space(1))) unsigned int*)(uintptr_t)g,
      (__attribute__((address_space(3))) unsigned int*)(uintptr_t)l, 16, 0, 0);
}
// logsigmoid(f) for f in (0,1): softplus series, |err| <= 2.5e-5
__device__ __forceinline__ float logsig01(float f) {
  float u = f * f;
  return -0.69314718f + 0.5f * f + u * (-0.125f + u * (0.0052083335f - u * 3.472222e-4f));
}

// ---------------------------------------------------------------------------
// 128x128-tile bf16 GEMM core (R7): BK=32, double-buffered in 32KB,
// 1 barrier/kt, loads age a full compute phase before the drain.
// ---------------------------------------------------------------------------
__device__ __forceinline__ void gemm128_core(const u16* __restrict__ Ag, const u16* __restrict__ Bg,
                                             u16* smem, f32x4 (&acc)[4][4]) {
  const int tid = threadIdx.x;
  const int lane = tid & 63, wave = tid >> 6;
  const int wm = (wave & 1) * 64, wn = (wave >> 1) * 64;
  const int r = lane & 15, quad = lane >> 4;
  const int xk = r & 3;
  const u16* baseA = smem + (wm + r) * 32 + ((quad ^ xk) & 3) * 8;
  const u16* baseB = smem + 4096 + (wn + r) * 32 + ((quad ^ xk) & 3) * 8;
  const int soff = (tid >> 2) * 1024 + (((tid & 3) ^ ((tid >> 2) & 3)) * 8);
  u16* dA = smem + wave * 512;           // + it*2048 + buf*8192
  u16* dB = smem + 4096 + wave * 512;
#pragma unroll
  for (int it = 0; it < 2; ++it) {
    async_load16(Ag + it * 65536 + soff, dA + it * 2048);
    async_load16(Bg + it * 65536 + soff, dB + it * 2048);
  }
#pragma unroll 2
  for (int kt = 0; kt < 32; ++kt) {
    const int cb = (kt & 1) * 8192;
    __syncthreads();
    if (kt < 31) {
      const int nb = ((kt + 1) & 1) * 8192;
      const u16* As = Ag + (kt + 1) * 32 + soff;
      const u16* Bs = Bg + (kt + 1) * 32 + soff;
#pragma unroll
      for (int it = 0; it < 2; ++it) {
        async_load16(As + it * 65536, dA + nb + it * 2048);
        async_load16(Bs + it * 65536, dB + nb + it * 2048);
      }
    }
    bf16x8 af[4], bv[4];
#pragma unroll
    for (int i = 0; i < 4; ++i) af[i] = *(const bf16x8*)(baseA + cb + i * 512);
#pragma unroll
    for (int j = 0; j < 4; ++j) bv[j] = *(const bf16x8*)(baseB + cb + j * 512);
#pragma unroll
    for (int i = 0; i < 4; ++i)
#pragma unroll
      for (int j = 0; j < 4; ++j)
        acc[i][j] = __builtin_amdgcn_mfma_f32_16x16x32_bf16(af[i], bv[j], acc[i][j], 0, 0, 0);
  }
}

// ---------------------------------------------------------------------------
// merged casts: blocks 0-8191 -> x; 8192-12287 -> weights (Wo folds norm_w)
__global__ __launch_bounds__(256) void cast_all(
    const float* __restrict__ x, const float* __restrict__ w0, const float* __restrict__ w1,
    const float* __restrict__ w2, const float* __restrict__ w3, const float* __restrict__ nw,
    u16* __restrict__ xd, u16* __restrict__ d0, u16* __restrict__ d1,
    u16* __restrict__ d2, u16* __restrict__ d3) {
  const int blk = blockIdx.x;
  const float* src;
  u16* dst;
  int i;
  bool fold = false;
  if (blk < 8192) {
    src = x; dst = xd; i = blk * 256 + threadIdx.x;
  } else {
    int wb = blk - 8192, which = wb >> 10;
    i = (wb & 1023) * 256 + threadIdx.x;
    src = which == 0 ? w0 : (which == 1 ? w1 : (which == 2 ? w2 : w3));
    dst = which == 0 ? d0 : (which == 1 ? d1 : (which == 2 ? d2 : d3));
    fold = (which == 3);
  }
  float4 v = ((const float4*)src)[i];
  if (fold) {
    float4 wv = ((const float4*)nw)[i & 255];
    v.x *= wv.x; v.y *= wv.y; v.z *= wv.z; v.w *= wv.w;
  }
  unsigned int lo = (unsigned)f2bf(v.x) | ((unsigned)f2bf(v.y) << 16);
  unsigned int hi = (unsigned)f2bf(v.z) | ((unsigned)f2bf(v.w) << 16);
  ((uint2*)dst)[i] = make_uint2(lo, hi);
}

// grid (64, 24): y/8 selects {Q,K,V}, y&7 = 128-col block
__global__ __launch_bounds__(256) void hgru_gemm_qkv(
    const u16* __restrict__ Xb, const u16* __restrict__ Wqb, const u16* __restrict__ Wkb,
    const u16* __restrict__ Wvb, u16* __restrict__ Qb, u16* __restrict__ Kb,
    u16* __restrict__ Vb) {
  __shared__ alignas(16) u16 smem[16384];
  const int which = blockIdx.y >> 3, bn = blockIdx.y & 7;
  const u16* W = which == 0 ? Wqb : (which == 1 ? Wkb : Wvb);
  const u16* Ag = Xb + (size_t)blockIdx.x * 128 * 1024;
  const u16* Bg = W + (size_t)bn * 128 * 1024;
  f32x4 acc[4][4] = {};
  gemm128_core(Ag, Bg, smem, acc);
  const int tid = threadIdx.x, lane = tid & 63, wave = tid >> 6;
  const int wm = (wave & 1) * 64, wn = (wave >> 1) * 64;
  const int r = lane & 15, quad = lane >> 4;
#pragma unroll
  for (int i = 0; i < 4; ++i)
#pragma unroll
    for (int j = 0; j < 4; ++j)
#pragma unroll
      for (int reg = 0; reg < 4; ++reg) {
        int m = blockIdx.x * 128 + wm + i * 16 + quad * 4 + reg;
        int n = bn * 128 + wn + j * 16 + r;
        size_t off = (size_t)m * 1024 + n;
        float z = acc[i][j][reg];
        if (which == 0) {
          Qb[off] = f2bf(z / (1.f + __expf(-z)));      // silu
        } else if (which == 1) {
          float ek = __expf(-z);
          Kb[off] = f2bf(ek / (1.f + ek));              // k = 1 - sigmoid(z)
        } else {
          Vb[off] = f2bf(z);
        }
      }
}

// ---------------------------------------------------------------------------
// Fused scan (R8 layout, 42496 B, 3 blocks/CU) + fused sumsq.
// grid 4096: vh = blk&1, c = (blk>>1)&63 (C=32), bh = blk>>7.
// ---------------------------------------------------------------------------
__global__ __launch_bounds__(256) void hgru_scan(
    const u16* __restrict__ Qg, const u16* __restrict__ Kg, const u16* __restrict__ Vg,
    u16* __restrict__ O, float* __restrict__ Ssum) {
  __shared__ alignas(16) char smem[42496];
  float* sb  = (float*)(smem);             // [32][129] cumsum    [0,16512)
  u16* sU    = (u16*)(smem);               // [64][136] U^T       [0,17408)  after transform-c
  u16* sKt   = (u16*)(smem + 17408);       // [128][40] phase1
  u16* sVt1  = (u16*)(smem + 27648);       // [64][40]  phase1
  u16* sQ    = (u16*)(smem + 17408);       // [32][136] phase2
  u16* sK    = (u16*)(smem + 26112);       // [32][136] phase2
  u16* sVt2  = (u16*)(smem + 34816);       // [64][40]
  u16* sAm   = (u16*)(smem + 39936);       // [32][40]

  const int tid = threadIdx.x, blk = blockIdx.x;
  const int vh = blk & 1, c = (blk >> 1) & 63, bh = blk >> 7, h = bh & 7, bb_ = bh >> 3;
  const size_t rb = (size_t)(bb_ * 2048 + c * 32) * 1024 + h * 128;
  const bool haveP = (c > 0);
  const size_t rb1 = haveP ? rb - 32 * 1024 : rb;

  const int lane = tid & 63, wave = tid >> 6;
  const int r = lane & 15, quad = lane >> 4;
  const int ts = tid & 31;
  const int g8 = tid >> 5;

  uint4 Q2[2], K2[2], K1[2], V2, V1;
#pragma unroll
  for (int it = 0; it < 2; ++it) {
    Q2[it] = *(const uint4*)(Qg + rb  + (size_t)ts * 1024 + (it * 8 + g8) * 8);
    K2[it] = *(const uint4*)(Kg + rb  + (size_t)ts * 1024 + (it * 8 + g8) * 8);
    K1[it] = *(const uint4*)(Kg + rb1 + (size_t)ts * 1024 + (it * 8 + g8) * 8);
  }
  V2 = *(const uint4*)(Vg + rb  + (size_t)ts * 1024 + vh * 64 + g8 * 8);
  V1 = *(const uint4*)(Vg + rb1 + (size_t)ts * 1024 + vh * 64 + g8 * 8);

  f32x4 accU[2][4] = {};
  const int vm = (wave & 1) * 32, in = (wave >> 1) * 64;

  if (haveP) {
    { const int col = tid & 127, half = tid >> 7;
      float run = 0.f;
      const size_t gb = rb1 + (size_t)(half * 16) * 1024 + col;
#pragma unroll
      for (int t = 0; t < 16; ++t) {
        float kv = bf2f(Kg[gb + (size_t)t * 1024]);
        run += logsig01(1.f - kv);
        sb[(half * 16 + t) * 129 + col] = run;
      } }
    __syncthreads();
    { if (tid >> 7) { const int col = tid & 127; float fix = sb[15 * 129 + col];
#pragma unroll
        for (int t = 16; t < 32; ++t) sb[t * 129 + col] += fix; } }
    __syncthreads();
#pragma unroll
    for (int it = 0; it < 2; ++it) {
      const int i8 = it * 8 + g8;
      const u16* kp = (const u16*)&K1[it];
#pragma unroll
      for (int e = 0; e < 8; ++e) {
        int i = i8 * 8 + e;
        float bs = sb[ts * 129 + i];
        float bC = sb[31 * 129 + i];
        sKt[i * 40 + ts] = f2bf(bf2f(kp[e]) * __expf(bC - bs));
      }
    }
    { const u16* vp = (const u16*)&V1;
#pragma unroll
      for (int e = 0; e < 8; ++e) sVt1[(g8 * 8 + e) * 40 + ts] = vp[e]; }
    __syncthreads();
#pragma unroll
    for (int mi = 0; mi < 2; ++mi) {
      bf16x8 af = *(const bf16x8*)(sVt1 + (vm + mi * 16 + r) * 40 + quad * 8);
#pragma unroll
      for (int nj = 0; nj < 4; ++nj) {
        bf16x8 bv = *(const bf16x8*)(sKt + (in + nj * 16 + r) * 40 + quad * 8);
        accU[mi][nj] = __builtin_amdgcn_mfma_f32_16x16x32_bf16(af, bv, accU[mi][nj], 0, 0, 0);
      }
    }
  }
  { const int col = tid & 127, half = tid >> 7;
    float run = 0.f;
    const size_t gb = rb + (size_t)(half * 16) * 1024 + col;
#pragma unroll
    for (int t = 0; t < 16; ++t) {
      float kv = bf2f(Kg[gb + (size_t)t * 1024]);
      run += logsig01(1.f - kv);
      sb[(half * 16 + t) * 129 + col] = run;
    } }
  __syncthreads();
  { if (tid >> 7) { const int col = tid & 127; float fix = sb[15 * 129 + col];
#pragma unroll
      for (int t = 16; t < 32; ++t) sb[t * 129 + col] += fix; } }
  __syncthreads();
#pragma unroll
  for (int it = 0; it < 2; ++it) {
    const int i8 = it * 8 + g8;
    const u16* qp = (const u16*)&Q2[it];
    const u16* kp = (const u16*)&K2[it];
    u16 qo[8], ko[8];
#pragma unroll
    for (int e = 0; e < 8; ++e) {
      int i = i8 * 8 + e;
      float bt = sb[ts * 129 + i];
      qo[e] = f2bf(bf2f(qp[e]) * __expf(bt));
      ko[e] = f2bf(bf2f(kp[e]) * __expf(-bt));
    }
    *(uint4*)(sQ + ts * 136 + i8 * 8) = *(const uint4*)qo;
    *(uint4*)(sK + ts * 136 + i8 * 8) = *(const uint4*)ko;
  }
  { const u16* vp = (const u16*)&V2;
#pragma unroll
    for (int e = 0; e < 8; ++e) sVt2[(g8 * 8 + e) * 40 + ts] = vp[e]; }
  __syncthreads();
  { const int mi = wave & 1, nj = wave >> 1;
    f32x4 a1 = {0.f, 0.f, 0.f, 0.f};
#pragma unroll
    for (int ks = 0; ks < 4; ++ks) {
      bf16x8 af = *(const bf16x8*)(sQ + (mi * 16 + r) * 136 + ks * 32 + quad * 8);
      bf16x8 bk = *(const bf16x8*)(sK + (nj * 16 + r) * 136 + ks * 32 + quad * 8);
      a1 = __builtin_amdgcn_mfma_f32_16x16x32_bf16(af, bk, a1, 0, 0, 0);
    }
#pragma unroll
    for (int reg = 0; reg < 4; ++reg) {
      int t = mi * 16 + quad * 4 + reg, s = nj * 16 + r;
      sAm[t * 40 + s] = (s <= t) ? f2bf(a1[reg]) : (u16)0;
    } }
  if (haveP) {
#pragma unroll
    for (int mi = 0; mi < 2; ++mi)
#pragma unroll
      for (int nj = 0; nj < 4; ++nj)
#pragma unroll
        for (int reg = 0; reg < 4; ++reg) {
          int vl = vm + mi * 16 + quad * 4 + reg;
          int i  = in + nj * 16 + r;
          sU[vl * 136 + i] = f2bf(accU[mi][nj][reg]);
        }
  }
  __syncthreads();
  // GEMM2 + fused sumsq
  { const int mi = wave & 1, no = (wave >> 1) * 32;
    bf16x8 af0 = *(const bf16x8*)(sAm + (mi * 16 + r) * 40 + quad * 8);
    bf16x8 afq[4];
    if (haveP) {
#pragma unroll
      for (int ks = 0; ks < 4; ++ks)
        afq[ks] = *(const bf16x8*)(sQ + (mi * 16 + r) * 136 + ks * 32 + quad * 8);
    }
    f32x4 ssq = {0.f, 0.f, 0.f, 0.f};
#pragma unroll
    for (int j = 0; j < 2; ++j) {
      f32x4 acc2 = {0.f, 0.f, 0.f, 0.f};
      bf16x8 bv0 = *(const bf16x8*)(sVt2 + (no + j * 16 + r) * 40 + quad * 8);
      acc2 = __builtin_amdgcn_mfma_f32_16x16x32_bf16(af0, bv0, acc2, 0, 0, 0);
      if (haveP) {
#pragma unroll
        for (int ks = 0; ks < 4; ++ks) {
          bf16x8 bs = *(const bf16x8*)(sU + (no + j * 16 + r) * 136 + ks * 32 + quad * 8);
          acc2 = __builtin_amdgcn_mfma_f32_16x16x32_bf16(afq[ks], bs, acc2, 0, 0, 0);
        }
      }
      ssq += acc2 * acc2;
#pragma unroll
      for (int reg = 0; reg < 4; ++reg) {
        int t = mi * 16 + quad * 4 + reg;
        int vg = vh * 64 + no + j * 16 + r;
        O[rb + (size_t)t * 1024 + vg] = f2bf(acc2[reg]);
      }
    }
    const int rowg = bb_ * 2048 + c * 32 + mi * 16 + quad * 4;
#pragma unroll
    for (int reg = 0; reg < 4; ++reg) {
      float v = ssq[reg];
      v += __shfl_xor(v, 1); v += __shfl_xor(v, 2);
      v += __shfl_xor(v, 4); v += __shfl_xor(v, 8);
      if (r == 0) atomicAdd(&Ssum[rowg + reg], v);
    } }
}

// out[m][n] = rsqrt(Ssum[m]/1024+eps) * (O @ Wo'^T)[m][n]; grid (64,8)
__global__ __launch_bounds__(256) void hgru_gemm_out(const u16* __restrict__ Ab,
                                                     const u16* __restrict__ Wob,
                                                     const float* __restrict__ Ssum,
                                                     float* __restrict__ out) {
  __shared__ alignas(16) u16 smem[16384];
  const u16* Ag = Ab + (size_t)blockIdx.x * 128 * 1024;
  const u16* Bg = Wob + (size_t)blockIdx.y * 128 * 1024;
  f32x4 acc[4][4] = {};
  gemm128_core(Ag, Bg, smem, acc);
  const int tid = threadIdx.x, lane = tid & 63, wave = tid >> 6;
  const int wm = (wave & 1) * 64, wn = (wave >> 1) * 64;
  const int r = lane & 15, quad = lane >> 4;
#pragma unroll
  for (int i = 0; i < 4; ++i)
#pragma unroll
    for (int reg = 0; reg < 4; ++reg) {
      int m = blockIdx.x * 128 + wm + i * 16 + quad * 4 + reg;
      float sm = rsqrtf(Ssum[m] * (1.f / 1024.f) + 1e-6f);
#pragma unroll
      for (int j = 0; j < 4; ++j) {
        int n = blockIdx.y * 128 + wn + j * 16 + r;
        out[(size_t)m * 1024 + n] = acc[i][j][reg] * sm;
      }
    }
}

// ---------------------------------------------------------------------------
extern "C" void kernel_launch(void* const* d_in, const int* in_sizes, int n_in,
                              void* d_out, int out_size, void* d_ws, size_t ws_size,
                              hipStream_t stream) {
  const float* x  = (const float*)d_in[0];
  const float* Wq = (const float*)d_in[1];
  const float* Wk = (const float*)d_in[2];
  const float* Wv = (const float*)d_in[3];
  const float* Wo = (const float*)d_in[4];
  const float* nw = (const float*)d_in[5];
  float* out = (float*)d_out;
  char* ws = (char*)d_ws;

  u16* Xb   = (u16*)(ws + 0);            // 16 MB
  u16* Wqb  = (u16*)(ws + 16777216);
  u16* Wkb  = (u16*)(ws + 18874368);
  u16* Wvb  = (u16*)(ws + 20971520);
  u16* Wob  = (u16*)(ws + 23068672);
  u16* Qb   = (u16*)(ws + 25165824);     // 16 MB
  u16* Kb   = (u16*)(ws + 41943040);     // 16 MB
  u16* Vb   = (u16*)(ws + 58720256);     // 16 MB
  u16* Obf  = (u16*)(ws + 75497472);     // 16 MB scan output
  float* Sv = (float*)(ws + 92274688);   // 32 KB row sum-of-squares

  cast_all<<<12288, 256, 0, stream>>>(x, Wq, Wk, Wv, Wo, nw, Xb, Wqb, Wkb, Wvb, Wob);
  hipMemsetAsync(Sv, 0, 8192 * sizeof(float), stream);

  dim3 gq(64, 24);
  hgru_gemm_qkv<<<gq, 256, 0, stream>>>(Xb, Wqb, Wkb, Wvb, Qb, Kb, Vb);
  hgru_scan<<<4096, 256, 0, stream>>>(Qb, Kb, Vb, Obf, Sv);
  dim3 go(64, 8);
  hgru_gemm_out<<<go, 256, 0, stream>>>(Obf, Wob, Sv, out);
}

// Round 11
// 228.632 us; speedup vs baseline: 1.0749x; 1.0423x over previous
//
#include <hip/hip_runtime.h>
#include <cstdint>
#include <cstddef>

// ---------------------------------------------------------------------------
// Hgru2 (GLA-style gated linear attention), B=4, N=2048, d=1024, h=8, hd=128
//   cast_all: x,W -> bf16 (Wo gets norm_w folded); zeroes Ssum
//   gemm_qkv: Q=silu(xWq^T), K=1-sigmoid(xWk^T) (bf16), V (bf16)
//   hgru_scan (C=32): recompute U_{c-1} from chunk c-1 (1-term state, decay
//       <= e^-10); O = tril(Qh Kt^T) V + Qh U; fused sumsq via atomicAdd.
//   gemm_out: out[m][n] = rsqrt(Ssum[m]/1024+eps) * (O @ (Wo . w)^T)[m][n]
// R11: scan rebuilt as a 4-barrier kernel: column-owner cumsum+transform in
//      ONE latency phase (no sb buffer, no fixup phases), U-GEMM+GEMM1 merged,
//      LDS 40448 B -> 4 blocks/CU (launch_bounds(256,4)), coalesced O-store
//      via LDS staging. memset folded into cast_all.
// ---------------------------------------------------------------------------

typedef unsigned short u16;
using f32x4  = __attribute__((ext_vector_type(4))) float;
using bf16x8 = __attribute__((ext_vector_type(8))) short;

__device__ __forceinline__ float bf2f(u16 u) {
  union { unsigned int i; float f; } v; v.i = ((unsigned int)u) << 16; return v.f;
}
__device__ __forceinline__ u16 f2bf(float f) {
  union { float f; unsigned int i; } v; v.f = f;
  unsigned int r = v.i + 0x7fffu + ((v.i >> 16) & 1u);
  return (u16)(r >> 16);
}
__device__ __forceinline__ void async_load16(const void* g, void* l) {
  __builtin_amdgcn_global_load_lds(
      (const __attribute__((address_space(1))) unsigned int*)(uintptr_t)g,
      (__attribute__((address_space(3))) unsigned int*)(uintptr_t)l, 16, 0, 0);
}
// logsigmoid(f) for f in (0,1): softplus series, |err| <= 2.5e-5
__device__ __forceinline__ float logsig01(float f) {
  float u = f * f;
  return -0.69314718f + 0.5f * f + u * (-0.125f + u * (0.0052083335f - u * 3.472222e-4f));
}

// ---------------------------------------------------------------------------
// 128x128-tile bf16 GEMM core (R7): BK=32, double-buffered in 32KB,
// 1 barrier/kt, loads age a full compute phase before the drain.
// ---------------------------------------------------------------------------
__device__ __forceinline__ void gemm128_core(const u16* __restrict__ Ag, const u16* __restrict__ Bg,
                                             u16* smem, f32x4 (&acc)[4][4]) {
  const int tid = threadIdx.x;
  const int lane = tid & 63, wave = tid >> 6;
  const int wm = (wave & 1) * 64, wn = (wave >> 1) * 64;
  const int r = lane & 15, quad = lane >> 4;
  const int xk = r & 3;
  const u16* baseA = smem + (wm + r) * 32 + ((quad ^ xk) & 3) * 8;
  const u16* baseB = smem + 4096 + (wn + r) * 32 + ((quad ^ xk) & 3) * 8;
  const int soff = (tid >> 2) * 1024 + (((tid & 3) ^ ((tid >> 2) & 3)) * 8);
  u16* dA = smem + wave * 512;           // + it*2048 + buf*8192
  u16* dB = smem + 4096 + wave * 512;
#pragma unroll
  for (int it = 0; it < 2; ++it) {
    async_load16(Ag + it * 65536 + soff, dA + it * 2048);
    async_load16(Bg + it * 65536 + soff, dB + it * 2048);
  }
#pragma unroll 2
  for (int kt = 0; kt < 32; ++kt) {
    const int cb = (kt & 1) * 8192;
    __syncthreads();
    if (kt < 31) {
      const int nb = ((kt + 1) & 1) * 8192;
      const u16* As = Ag + (kt + 1) * 32 + soff;
      const u16* Bs = Bg + (kt + 1) * 32 + soff;
#pragma unroll
      for (int it = 0; it < 2; ++it) {
        async_load16(As + it * 65536, dA + nb + it * 2048);
        async_load16(Bs + it * 65536, dB + nb + it * 2048);
      }
    }
    bf16x8 af[4], bv[4];
#pragma unroll
    for (int i = 0; i < 4; ++i) af[i] = *(const bf16x8*)(baseA + cb + i * 512);
#pragma unroll
    for (int j = 0; j < 4; ++j) bv[j] = *(const bf16x8*)(baseB + cb + j * 512);
#pragma unroll
    for (int i = 0; i < 4; ++i)
#pragma unroll
      for (int j = 0; j < 4; ++j)
        acc[i][j] = __builtin_amdgcn_mfma_f32_16x16x32_bf16(af[i], bv[j], acc[i][j], 0, 0, 0);
  }
}

// ---------------------------------------------------------------------------
// merged casts + Ssum zero: blocks 0-8191 -> x; 8192-12287 -> weights
// (Wo folds norm_w); 12288-12319 -> zero Ssum (8192 f32).
__global__ __launch_bounds__(256) void cast_all(
    const float* __restrict__ x, const float* __restrict__ w0, const float* __restrict__ w1,
    const float* __restrict__ w2, const float* __restrict__ w3, const float* __restrict__ nw,
    u16* __restrict__ xd, u16* __restrict__ d0, u16* __restrict__ d1,
    u16* __restrict__ d2, u16* __restrict__ d3, float* __restrict__ Sv) {
  const int blk = blockIdx.x;
  if (blk >= 12288) {
    Sv[(blk - 12288) * 256 + threadIdx.x] = 0.f;
    return;
  }
  const float* src;
  u16* dst;
  int i;
  bool fold = false;
  if (blk < 8192) {
    src = x; dst = xd; i = blk * 256 + threadIdx.x;
  } else {
    int wb = blk - 8192, which = wb >> 10;
    i = (wb & 1023) * 256 + threadIdx.x;
    src = which == 0 ? w0 : (which == 1 ? w1 : (which == 2 ? w2 : w3));
    dst = which == 0 ? d0 : (which == 1 ? d1 : (which == 2 ? d2 : d3));
    fold = (which == 3);
  }
  float4 v = ((const float4*)src)[i];
  if (fold) {
    float4 wv = ((const float4*)nw)[i & 255];
    v.x *= wv.x; v.y *= wv.y; v.z *= wv.z; v.w *= wv.w;
  }
  unsigned int lo = (unsigned)f2bf(v.x) | ((unsigned)f2bf(v.y) << 16);
  unsigned int hi = (unsigned)f2bf(v.z) | ((unsigned)f2bf(v.w) << 16);
  ((uint2*)dst)[i] = make_uint2(lo, hi);
}

// grid (64, 24): y/8 selects {Q,K,V}, y&7 = 128-col block
__global__ __launch_bounds__(256) void hgru_gemm_qkv(
    const u16* __restrict__ Xb, const u16* __restrict__ Wqb, const u16* __restrict__ Wkb,
    const u16* __restrict__ Wvb, u16* __restrict__ Qb, u16* __restrict__ Kb,
    u16* __restrict__ Vb) {
  __shared__ alignas(16) u16 smem[16384];
  const int which = blockIdx.y >> 3, bn = blockIdx.y & 7;
  const u16* W = which == 0 ? Wqb : (which == 1 ? Wkb : Wvb);
  const u16* Ag = Xb + (size_t)blockIdx.x * 128 * 1024;
  const u16* Bg = W + (size_t)bn * 128 * 1024;
  f32x4 acc[4][4] = {};
  gemm128_core(Ag, Bg, smem, acc);
  const int tid = threadIdx.x, lane = tid & 63, wave = tid >> 6;
  const int wm = (wave & 1) * 64, wn = (wave >> 1) * 64;
  const int r = lane & 15, quad = lane >> 4;
#pragma unroll
  for (int i = 0; i < 4; ++i)
#pragma unroll
    for (int j = 0; j < 4; ++j)
#pragma unroll
      for (int reg = 0; reg < 4; ++reg) {
        int m = blockIdx.x * 128 + wm + i * 16 + quad * 4 + reg;
        int n = bn * 128 + wn + j * 16 + r;
        size_t off = (size_t)m * 1024 + n;
        float z = acc[i][j][reg];
        if (which == 0) {
          Qb[off] = f2bf(z / (1.f + __expf(-z)));      // silu
        } else if (which == 1) {
          float ek = __expf(-z);
          Kb[off] = f2bf(ek / (1.f + ek));              // k = 1 - sigmoid(z)
        } else {
          Vb[off] = f2bf(z);
        }
      }
}

// ---------------------------------------------------------------------------
// Fused scan, 4-barrier structure, LDS 40448 B -> 4 blocks/CU.
// grid 4096: vh = blk&1, c = (blk>>1)&63 (C=32), bh = blk>>7.
// P0: column-owner cumsum+transforms (the ONLY global-latency phase)
//     half 0 (tid<128, col i): chunk c-1, 2-pass -> sKt[i][s] = k*exp(bC-b_s)
//     half 1 (col j): chunk c, 1-pass -> sQ[t][j]=q*exp(b), sK[t][j]=k*exp(-b)
//     all: V^T scatters from uint4-prefetched regs.
// P1: U-GEMM (regs) + GEMM1 -> sAm.   P2: spill U -> sU (overlays dead sKt).
// P3: GEMM2 + ssq atomics + stage O tile in sO.   P4: coalesced uint4 O-store.
// ---------------------------------------------------------------------------
__global__ __launch_bounds__(256, 4) void hgru_scan(
    const u16* __restrict__ Qg, const u16* __restrict__ Kg, const u16* __restrict__ Vg,
    u16* __restrict__ O, float* __restrict__ Ssum) {
  __shared__ alignas(16) char smem[40448];
  u16* sKt  = (u16*)(smem);                // [128][40] khat^T   [0,10240)
  u16* sVt1 = (u16*)(smem + 10240);        // [64][40]  V^T c-1  [10240,15360)
  u16* sK   = (u16*)(smem + 15360);        // [32][136] Kt       [15360,24064)
  u16* sQ   = (u16*)(smem + 24064);        // [32][136] Qh       [24064,32768)
  u16* sVt2 = (u16*)(smem + 32768);        // [64][40]  V^T c    [32768,37888)
  u16* sAm  = (u16*)(smem + 37888);        // [32][40]  masked A [37888,40448)
  u16* sU   = (u16*)(smem);                // [64][136] U^T      (after B1, over dead sKt+sVt1)
  u16* sO   = (u16*)(smem + 17408);        // [32][72]  O tile   (after B1, in dead sK head)

  const int tid = threadIdx.x, blk = blockIdx.x;
  const int vh = blk & 1, c = (blk >> 1) & 63, bh = blk >> 7, h = bh & 7, bb_ = bh >> 3;
  const size_t rb = (size_t)(bb_ * 2048 + c * 32) * 1024 + h * 128;
  const bool haveP = (c > 0);
  const size_t rb1 = haveP ? rb - 32 * 1024 : rb;

  const int lane = tid & 63, wave = tid >> 6;
  const int r = lane & 15, quad = lane >> 4;
  const int ts = tid & 31, g8 = tid >> 5;

  // V prefetch (uint4) + V^T scatters
  uint4 V2 = *(const uint4*)(Vg + rb  + (size_t)ts * 1024 + vh * 64 + g8 * 8);
  uint4 V1 = *(const uint4*)(Vg + rb1 + (size_t)ts * 1024 + vh * 64 + g8 * 8);
  { const u16* vp = (const u16*)&V2;
#pragma unroll
    for (int e = 0; e < 8; ++e) sVt2[(g8 * 8 + e) * 40 + ts] = vp[e]; }
  if (haveP) {
    const u16* vp = (const u16*)&V1;
#pragma unroll
    for (int e = 0; e < 8; ++e) sVt1[(g8 * 8 + e) * 40 + ts] = vp[e];
  }

  // P0: column cumsum + transforms
  const int col = tid & 127;
  if (tid < 128) {
    if (haveP) {
      const u16* kc = Kg + rb1 + col;
      unsigned int kraw[16];
      float bC = 0.f;
#pragma unroll
      for (int t = 0; t < 16; ++t) {
        unsigned int a = kc[(size_t)(2 * t) * 1024];
        unsigned int b = kc[(size_t)(2 * t + 1) * 1024];
        kraw[t] = a | (b << 16);
        bC += logsig01(1.f - bf2f((u16)a)) + logsig01(1.f - bf2f((u16)b));
      }
      float run = 0.f;
#pragma unroll
      for (int t = 0; t < 16; ++t) {
        float ka = bf2f((u16)(kraw[t] & 0xffff));
        float kb = bf2f((u16)(kraw[t] >> 16));
        run += logsig01(1.f - ka);
        sKt[col * 40 + 2 * t]     = f2bf(ka * __expf(bC - run));
        run += logsig01(1.f - kb);
        sKt[col * 40 + 2 * t + 1] = f2bf(kb * __expf(bC - run));
      }
    }
  } else {
    const u16* kc = Kg + rb + col;
    const u16* qc = Qg + rb + col;
    float run = 0.f;
#pragma unroll
    for (int t = 0; t < 32; ++t) {
      u16 ku = kc[(size_t)t * 1024];
      u16 qu = qc[(size_t)t * 1024];
      float kv = bf2f(ku);
      run += logsig01(1.f - kv);
      sQ[t * 136 + col] = f2bf(bf2f(qu) * __expf(run));
      sK[t * 136 + col] = f2bf(kv * __expf(-run));
    }
  }
  __syncthreads();  // B0

  // P1: U-GEMM (into regs) + GEMM1 -> sAm
  f32x4 accU[2][4] = {};
  const int vm = (wave & 1) * 32, in = (wave >> 1) * 64;
  if (haveP) {
#pragma unroll
    for (int mi = 0; mi < 2; ++mi) {
      bf16x8 af = *(const bf16x8*)(sVt1 + (vm + mi * 16 + r) * 40 + quad * 8);
#pragma unroll
      for (int nj = 0; nj < 4; ++nj) {
        bf16x8 bv = *(const bf16x8*)(sKt + (in + nj * 16 + r) * 40 + quad * 8);
        accU[mi][nj] = __builtin_amdgcn_mfma_f32_16x16x32_bf16(af, bv, accU[mi][nj], 0, 0, 0);
      }
    }
  }
  { const int mi = wave & 1, nj = wave >> 1;
    f32x4 a1 = {0.f, 0.f, 0.f, 0.f};
#pragma unroll
    for (int ks = 0; ks < 4; ++ks) {
      bf16x8 af = *(const bf16x8*)(sQ + (mi * 16 + r) * 136 + ks * 32 + quad * 8);
      bf16x8 bk = *(const bf16x8*)(sK + (nj * 16 + r) * 136 + ks * 32 + quad * 8);
      a1 = __builtin_amdgcn_mfma_f32_16x16x32_bf16(af, bk, a1, 0, 0, 0);
    }
#pragma unroll
    for (int reg = 0; reg < 4; ++reg) {
      int t = mi * 16 + quad * 4 + reg, s = nj * 16 + r;
      sAm[t * 40 + s] = (s <= t) ? f2bf(a1[reg]) : (u16)0;
    } }
  __syncthreads();  // B1

  // P2: spill U accumulator -> sU (overlays dead sKt/sVt1)
  if (haveP) {
#pragma unroll
    for (int mi = 0; mi < 2; ++mi)
#pragma unroll
      for (int nj = 0; nj < 4; ++nj)
#pragma unroll
        for (int reg = 0; reg < 4; ++reg) {
          int vl = vm + mi * 16 + quad * 4 + reg;
          int i  = in + nj * 16 + r;
          sU[vl * 136 + i] = f2bf(accU[mi][nj][reg]);
        }
  }
  __syncthreads();  // B2

  // P3: GEMM2 + fused sumsq + stage O tile
  { const int mi = wave & 1, no = (wave >> 1) * 32;
    bf16x8 af0 = *(const bf16x8*)(sAm + (mi * 16 + r) * 40 + quad * 8);
    bf16x8 afq[4];
    if (haveP) {
#pragma unroll
      for (int ks = 0; ks < 4; ++ks)
        afq[ks] = *(const bf16x8*)(sQ + (mi * 16 + r) * 136 + ks * 32 + quad * 8);
    }
    f32x4 ssq = {0.f, 0.f, 0.f, 0.f};
#pragma unroll
    for (int j = 0; j < 2; ++j) {
      f32x4 acc2 = {0.f, 0.f, 0.f, 0.f};
      bf16x8 bv0 = *(const bf16x8*)(sVt2 + (no + j * 16 + r) * 40 + quad * 8);
      acc2 = __builtin_amdgcn_mfma_f32_16x16x32_bf16(af0, bv0, acc2, 0, 0, 0);
      if (haveP) {
#pragma unroll
        for (int ks = 0; ks < 4; ++ks) {
          bf16x8 bs = *(const bf16x8*)(sU + (no + j * 16 + r) * 136 + ks * 32 + quad * 8);
          acc2 = __builtin_amdgcn_mfma_f32_16x16x32_bf16(afq[ks], bs, acc2, 0, 0, 0);
        }
      }
      ssq += acc2 * acc2;
#pragma unroll
      for (int reg = 0; reg < 4; ++reg) {
        int t = mi * 16 + quad * 4 + reg;
        sO[t * 72 + no + j * 16 + r] = f2bf(acc2[reg]);
      }
    }
    const int rowg = bb_ * 2048 + c * 32 + mi * 16 + quad * 4;
#pragma unroll
    for (int reg = 0; reg < 4; ++reg) {
      float v = ssq[reg];
      v += __shfl_xor(v, 1); v += __shfl_xor(v, 2);
      v += __shfl_xor(v, 4); v += __shfl_xor(v, 8);
      if (r == 0) atomicAdd(&Ssum[rowg + reg], v);
    } }
  __syncthreads();  // B3

  // P4: coalesced O store (uint4: 128B per 8 threads)
  { const int row = tid >> 3, seg = tid & 7;
    *(uint4*)(O + rb + (size_t)row * 1024 + vh * 64 + seg * 8) =
        *(const uint4*)(sO + row * 72 + seg * 8); }
}

// out[m][n] = rsqrt(Ssum[m]/1024+eps) * (O @ Wo'^T)[m][n]; grid (64,8)
__global__ __launch_bounds__(256) void hgru_gemm_out(const u16* __restrict__ Ab,
                                                     const u16* __restrict__ Wob,
                                                     const float* __restrict__ Ssum,
                                                     float* __restrict__ out) {
  __shared__ alignas(16) u16 smem[16384];
  const u16* Ag = Ab + (size_t)blockIdx.x * 128 * 1024;
  const u16* Bg = Wob + (size_t)blockIdx.y * 128 * 1024;
  f32x4 acc[4][4] = {};
  gemm128_core(Ag, Bg, smem, acc);
  const int tid = threadIdx.x, lane = tid & 63, wave = tid >> 6;
  const int wm = (wave & 1) * 64, wn = (wave >> 1) * 64;
  const int r = lane & 15, quad = lane >> 4;
#pragma unroll
  for (int i = 0; i < 4; ++i)
#pragma unroll
    for (int reg = 0; reg < 4; ++reg) {
      int m = blockIdx.x * 128 + wm + i * 16 + quad * 4 + reg;
      float sm = rsqrtf(Ssum[m] * (1.f / 1024.f) + 1e-6f);
#pragma unroll
      for (int j = 0; j < 4; ++j) {
        int n = blockIdx.y * 128 + wn + j * 16 + r;
        out[(size_t)m * 1024 + n] = acc[i][j][reg] * sm;
      }
    }
}

// ---------------------------------------------------------------------------
extern "C" void kernel_launch(void* const* d_in, const int* in_sizes, int n_in,
                              void* d_out, int out_size, void* d_ws, size_t ws_size,
                              hipStream_t stream) {
  const float* x  = (const float*)d_in[0];
  const float* Wq = (const float*)d_in[1];
  const float* Wk = (const float*)d_in[2];
  const float* Wv = (const float*)d_in[3];
  const float* Wo = (const float*)d_in[4];
  const float* nw = (const float*)d_in[5];
  float* out = (float*)d_out;
  char* ws = (char*)d_ws;

  u16* Xb   = (u16*)(ws + 0);            // 16 MB
  u16* Wqb  = (u16*)(ws + 16777216);
  u16* Wkb  = (u16*)(ws + 18874368);
  u16* Wvb  = (u16*)(ws + 20971520);
  u16* Wob  = (u16*)(ws + 23068672);
  u16* Qb   = (u16*)(ws + 25165824);     // 16 MB
  u16* Kb   = (u16*)(ws + 41943040);     // 16 MB
  u16* Vb   = (u16*)(ws + 58720256);     // 16 MB
  u16* Obf  = (u16*)(ws + 75497472);     // 16 MB scan output
  float* Sv = (float*)(ws + 92274688);   // 32 KB row sum-of-squares

  cast_all<<<12320, 256, 0, stream>>>(x, Wq, Wk, Wv, Wo, nw, Xb, Wqb, Wkb, Wvb, Wob, Sv);

  dim3 gq(64, 24);
  hgru_gemm_qkv<<<gq, 256, 0, stream>>>(Xb, Wqb, Wkb, Wvb, Qb, Kb, Vb);
  hgru_scan<<<4096, 256, 0, stream>>>(Qb, Kb, Vb, Obf, Sv);
  dim3 go(64, 8);
  hgru_gemm_out<<<go, 256, 0, stream>>>(Obf, Wob, Sv, out);
}